// Round 1
// baseline (304.738 us; speedup 1.0000x reference)
//
#include <hip/hip_runtime.h>

// ROIAlign forward, matches the JAX reference exactly:
//   PH=PW=7, SCALE=0.25, SR=2, ALIGNED=true
//   input [B=4, C=256, H=200, W=200] fp32, rois [N,5] fp32 (b,x1,y1,x2,y2)
//   output [N, C, 7, 7] fp32
//
// Baseline structure: one thread per output element, flat idx ordering
// ((n*C + c)*49 + bin) so a wave's lanes share one ROI's channel plane(s)
// -> gathers cluster in a ~5KB region per plane (L1-friendly).
// Validity mask folded into interp weights (no divergence); indices always
// clamped in-bounds per the reference's at_edge logic.

#define R_PH 7
#define R_PW 7
#define R_SR 2
#define R_SCALE 0.25f
#define R_B 4
#define R_C 256
#define R_H 200
#define R_W 200

__device__ __forceinline__ void axis_sample(float start, float bin, int p, int s, int size,
                                            int& lo, int& hi, float& wlo, float& whi) {
    // coord = start + p*bin + (s+0.5)*bin/SR   (same grouping as reference)
    float coord = (start + (float)p * bin) + ((float)s + 0.5f) * bin * (1.0f / R_SR);
    bool valid = (coord >= -1.0f) && (coord <= (float)size);
    float c = fmaxf(coord, 0.0f);
    int lo_raw = (int)floorf(c);
    bool at_edge = lo_raw >= size - 1;
    lo = at_edge ? size - 1 : lo_raw;
    hi = at_edge ? size - 1 : lo_raw + 1;
    float cv = at_edge ? (float)(size - 1) : c;
    float frac = cv - (float)lo;          // weight toward hi
    whi = valid ? frac : 0.0f;
    wlo = valid ? (1.0f - frac) : 0.0f;
}

__global__ void __launch_bounds__(256)
roi_align_fwd(const float* __restrict__ input,
              const float* __restrict__ rois,
              float* __restrict__ out, int total) {
    int idx = blockIdx.x * blockDim.x + threadIdx.x;
    if (idx >= total) return;

    int pw = idx % R_PW;
    int ph = (idx / R_PW) % R_PH;
    int c  = (idx / (R_PW * R_PH)) % R_C;
    int n  = idx / (R_PW * R_PH * R_C);

    const float* r = rois + (size_t)n * 5;
    int   b  = (int)r[0];
    float sx = r[1] * R_SCALE - 0.5f;
    float sy = r[2] * R_SCALE - 0.5f;
    float ex = r[3] * R_SCALE - 0.5f;
    float ey = r[4] * R_SCALE - 0.5f;
    float bin_w = (ex - sx) * (1.0f / R_PW);
    float bin_h = (ey - sy) * (1.0f / R_PH);

    const float* plane = input + (size_t)(b * R_C + c) * (R_H * R_W);

    int   ylo[R_SR], yhi[R_SR], xlo[R_SR], xhi[R_SR];
    float wylo[R_SR], wyhi[R_SR], wxlo[R_SR], wxhi[R_SR];
#pragma unroll
    for (int s = 0; s < R_SR; ++s) {
        axis_sample(sy, bin_h, ph, s, R_H, ylo[s], yhi[s], wylo[s], wyhi[s]);
        axis_sample(sx, bin_w, pw, s, R_W, xlo[s], xhi[s], wxlo[s], wxhi[s]);
    }

    float acc = 0.0f;
#pragma unroll
    for (int ys = 0; ys < R_SR; ++ys) {
        const float* row_lo = plane + ylo[ys] * R_W;
        const float* row_hi = plane + yhi[ys] * R_W;
#pragma unroll
        for (int xs = 0; xs < R_SR; ++xs) {
            float fll = row_lo[xlo[xs]];
            float flh = row_lo[xhi[xs]];
            float fhl = row_hi[xlo[xs]];
            float fhh = row_hi[xhi[xs]];
            acc += wylo[ys] * (wxlo[xs] * fll + wxhi[xs] * flh)
                 + wyhi[ys] * (wxlo[xs] * fhl + wxhi[xs] * fhh);
        }
    }
    out[idx] = acc * (1.0f / (R_SR * R_SR));
}

extern "C" void kernel_launch(void* const* d_in, const int* in_sizes, int n_in,
                              void* d_out, int out_size, void* d_ws, size_t ws_size,
                              hipStream_t stream) {
    const float* input = (const float*)d_in[0];
    const float* rois  = (const float*)d_in[1];
    float* out = (float*)d_out;
    int total = out_size;  // N * C * PH * PW
    int block = 256;
    int grid = (total + block - 1) / block;
    roi_align_fwd<<<grid, block, 0, stream>>>(input, rois, out, total);
}